// Round 1
// baseline (4370.175 us; speedup 1.0000x reference)
//
#include <hip/hip_runtime.h>
#include <stdint.h>

// LSTM scan: B=4096 rows, T=2048 steps, H1=H2=128.
// 256 blocks x 512 threads (8 waves). Block owns 16 batch rows, iterates all T steps.
// Wave w owns hidden-unit group [16w,16w+16) for BOTH cells (4 gate tiles of 16 cols).
// MFMA 16x16x32 bf16. C/D: col=lane&15, row=(lane>>4)*4+reg (m89-verified).
// A-frag: A[row=l&15][k=(l>>4)*8+j]; B-frag: B[k=(l>>4)*8+j][col=l&15].
// cell-1 weights: LDS (frag-order, 128KB). cell-2 weights: registers (128 VGPR/lane).
// h1/h2: LDS in frag-order; h2 double-buffered -> 2 barriers/step. c1/c2: f32 regs.

#define TT   2048
#define BM   16
#define XCH  64

typedef __attribute__((ext_vector_type(8))) short short8;
typedef __attribute__((ext_vector_type(4))) float f32x4;

__device__ inline short f2bf(float f) {
  union { float f; uint32_t u; } v; v.f = f;
  uint32_t r = v.u + 0x7FFFu + ((v.u >> 16) & 1u);   // RNE
  return (short)(r >> 16);
}

__device__ inline float sigm(float x) {
  float e = __builtin_amdgcn_exp2f(x * -1.44269504089f);
  return __builtin_amdgcn_rcpf(1.0f + e);
}

__device__ inline float tanh_(float x) {
  float e = __builtin_amdgcn_exp2f(x * 2.88539008178f);  // exp(2x)
  return 1.0f - 2.0f * __builtin_amdgcn_rcpf(e + 1.0f);
}

__global__ __launch_bounds__(512, 2)
void lstm_fused(const float* __restrict__ x,
                const float* __restrict__ Wih1, const float* __restrict__ Whh1,
                const float* __restrict__ bih1, const float* __restrict__ bhh1,
                const float* __restrict__ Wih2, const float* __restrict__ Whh2,
                const float* __restrict__ bih2, const float* __restrict__ bhh2,
                const float* __restrict__ W1, const float* __restrict__ b1,
                const float* __restrict__ W2, const float* __restrict__ b2,
                float* __restrict__ out)
{
  __shared__ short blds[65536];      // cell-1 B-frags: 32 tiles x 4 kk x 64 lanes x 8  (128KB)
  __shared__ short h1f[2048];        // h1 frags: 4 kk x 64 lanes x 8                    (4KB)
  __shared__ short h2f[2][2048];     // h2 frags, double-buffered                        (8KB)
  __shared__ short w12s[2048];       // [W1;W2] packed 16-col B tile                     (4KB)
  __shared__ float xbuf[2][BM][XCH]; // x chunk, double-buffered                         (8KB)

  const int tid = threadIdx.x;
  const int w   = tid >> 6;
  const int l   = tid & 63;
  const int lr  = l & 15;
  const int lg  = l >> 4;
  const int rb  = blockIdx.x * BM;

  // ---- prologue ----
  for (int i = tid; i < 2048; i += 512) { h1f[i] = 0; h2f[0][i] = 0; h2f[1][i] = 0; }

  if (tid < 256) {                   // x chunk 0
    int row = tid >> 4, q = tid & 15;
    *(float4*)&xbuf[0][row][q * 4] = *(const float4*)&x[(size_t)(rb + row) * TT + q * 4];
  }

  // cell-1 weights -> LDS frag order: B[k][col] = Whh1[col][k]
  #pragma unroll
  for (int g = 0; g < 4; ++g) {
    int col = g * 128 + w * 16 + lr;
    #pragma unroll
    for (int kk = 0; kk < 4; ++kk) {
      int k0 = kk * 32 + lg * 8;
      const float* src = Whh1 + col * 128 + k0;
      short8 v;
      #pragma unroll
      for (int j = 0; j < 8; ++j) v[j] = f2bf(src[j]);
      *(short8*)&blds[(((g * 8 + w) * 4 + kk) * 64 + l) * 8] = v;
    }
  }

  // W1 (cols 0-7) + W2 (cols 8-15) -> one LDS B tile
  if (w == 0) {
    const float* srcw = (lr < 8) ? (W1 + lr * 128) : (W2 + (lr - 8) * 128);
    #pragma unroll
    for (int kk = 0; kk < 4; ++kk) {
      int k0 = kk * 32 + lg * 8;
      short8 v;
      #pragma unroll
      for (int j = 0; j < 8; ++j) v[j] = f2bf(srcw[k0 + j]);
      *(short8*)&w12s[(kk * 64 + l) * 8] = v;
    }
  }

  // cell-2 weights -> registers: B[k][col], k<128 from Wih2, k>=128 from Whh2
  short8 wf[4][8];
  #pragma unroll
  for (int g = 0; g < 4; ++g) {
    int col = g * 128 + w * 16 + lr;
    #pragma unroll
    for (int kk = 0; kk < 8; ++kk) {
      int k0 = kk * 32 + lg * 8;
      const float* src = (kk < 4) ? (Wih2 + col * 128 + k0)
                                  : (Whh2 + col * 128 + (k0 - 128));
      short8 v;
      #pragma unroll
      for (int j = 0; j < 8; ++j) v[j] = f2bf(src[j]);
      wf[g][kk] = v;
    }
  }

  float bias1v[4], bias2v[4], wih1v[4];
  #pragma unroll
  for (int g = 0; g < 4; ++g) {
    int col = g * 128 + w * 16 + lr;
    bias1v[g] = bih1[col] + bhh1[col];
    bias2v[g] = bih2[col] + bhh2[col];
    wih1v[g]  = Wih1[col];           // Wih1 is (512,1)
  }
  const float outb = (lr < 8) ? b1[lr] : b2[lr - 8];

  // frag-order address for h[unit u][row]: base + row*8 shorts
  const int u     = w * 16 + lr;
  const int hbase = (u >> 5) * 512 + ((u >> 3) & 3) * 128 + (u & 7);

  float c1[4] = {0.f, 0.f, 0.f, 0.f};
  float c2[4] = {0.f, 0.f, 0.f, 0.f};

  float* outp = out + 32768;         // outputs region; out[0:32768] = output_cyto

  __syncthreads();

  for (int t = 0; t < TT; ++t) {
    // ---- phase 1: gates1 = h1_prev @ Whh1^T ----
    f32x4 acc[4];
    #pragma unroll
    for (int g = 0; g < 4; ++g) acc[g] = (f32x4){0.f, 0.f, 0.f, 0.f};
    #pragma unroll
    for (int kk = 0; kk < 4; ++kk) {
      short8 a = *(short8*)&h1f[(kk * 64 + l) * 8];
      #pragma unroll
      for (int g = 0; g < 4; ++g) {
        short8 bfr = *(short8*)&blds[(((g * 8 + w) * 4 + kk) * 64 + l) * 8];
        acc[g] = __builtin_amdgcn_mfma_f32_16x16x32_bf16(a, bfr, acc[g], 0, 0, 0);
      }
    }
    float h1n[4];
    {
      const float* xr = &xbuf[(t >> 6) & 1][0][t & 63];
      #pragma unroll
      for (int r = 0; r < 4; ++r) {
        float xv = xr[(lg * 4 + r) * XCH];
        float vi = sigm (acc[0][r] + xv * wih1v[0] + bias1v[0]);
        float vf = sigm (acc[1][r] + xv * wih1v[1] + bias1v[1]);
        float vg = tanh_(acc[2][r] + xv * wih1v[2] + bias1v[2]);
        float vo = sigm (acc[3][r] + xv * wih1v[3] + bias1v[3]);
        c1[r]  = vf * c1[r] + vi * vg;
        h1n[r] = vo * tanh_(c1[r]);
      }
    }
    __syncthreads();                                   // B1: all reads of h1^{t-1} done
    #pragma unroll
    for (int r = 0; r < 4; ++r)
      h1f[hbase + (lg * 4 + r) * 8] = f2bf(h1n[r]);
    if (((t + 1) & 63) == 0 && (t + 1) < TT && tid < 256) {   // prefetch next x chunk
      int row = tid >> 4, q = tid & 15;
      *(float4*)&xbuf[((t + 1) >> 6) & 1][row][q * 4] =
          *(const float4*)&x[(size_t)(rb + row) * TT + (t + 1) + q * 4];
    }
    __syncthreads();                                   // B2: h1^t visible

    // ---- phase 2: gates2 = [h1^t, h2^{t-1}] @ [Wih2,Whh2]^T ----
    short8 a2[8];
    #pragma unroll
    for (int kk = 0; kk < 4; ++kk)
      a2[kk] = *(short8*)&h1f[(kk * 64 + l) * 8];
    const short* h2r = h2f[(t + 1) & 1];               // h2^{t-1}
    #pragma unroll
    for (int kk = 0; kk < 4; ++kk)
      a2[4 + kk] = *(short8*)&h2r[(kk * 64 + l) * 8];
    #pragma unroll
    for (int g = 0; g < 4; ++g) acc[g] = (f32x4){0.f, 0.f, 0.f, 0.f};
    #pragma unroll
    for (int kk = 0; kk < 8; ++kk) {
      #pragma unroll
      for (int g = 0; g < 4; ++g)
        acc[g] = __builtin_amdgcn_mfma_f32_16x16x32_bf16(a2[kk], wf[g][kk], acc[g], 0, 0, 0);
    }

    // out(t-1) = h2^{t-1} @ [W1;W2]^T + b1 (rotating wave; reuses a2[4..7])
    if (w == (t & 7) && t > 0) {
      f32x4 ao = (f32x4){0.f, 0.f, 0.f, 0.f};
      #pragma unroll
      for (int kk = 0; kk < 4; ++kk) {
        short8 bfr = *(short8*)&w12s[(kk * 64 + l) * 8];
        ao = __builtin_amdgcn_mfma_f32_16x16x32_bf16(a2[4 + kk], bfr, ao, 0, 0, 0);
      }
      if (lr < 8) {
        #pragma unroll
        for (int r = 0; r < 4; ++r)
          outp[((size_t)(rb + lg * 4 + r) * TT + (t - 1)) * 8 + lr] = ao[r] + outb;
      }
    }

    short* h2w = h2f[t & 1];                           // h2^t
    #pragma unroll
    for (int r = 0; r < 4; ++r) {
      float vi = sigm (acc[0][r] + bias2v[0]);
      float vf = sigm (acc[1][r] + bias2v[1]);
      float vg = tanh_(acc[2][r] + bias2v[2]);
      float vo = sigm (acc[3][r] + bias2v[3]);
      c2[r] = vf * c2[r] + vi * vg;
      float h2n = vo * tanh_(c2[r]);
      h2w[hbase + (lg * 4 + r) * 8] = f2bf(h2n);
    }
  }

  __syncthreads();
  // out(T-1) and output_cyto = h2_final @ W2^T + b2
  if (w == 0) {
    const short* h2r = h2f[(TT - 1) & 1];
    f32x4 ao = (f32x4){0.f, 0.f, 0.f, 0.f};
    #pragma unroll
    for (int kk = 0; kk < 4; ++kk) {
      short8 a   = *(short8*)&h2r[(kk * 64 + l) * 8];
      short8 bfr = *(short8*)&w12s[(kk * 64 + l) * 8];
      ao = __builtin_amdgcn_mfma_f32_16x16x32_bf16(a, bfr, ao, 0, 0, 0);
    }
    #pragma unroll
    for (int r = 0; r < 4; ++r) {
      int rowg = rb + lg * 4 + r;
      float v = ao[r] + outb;
      if (lr < 8)
        outp[((size_t)rowg * TT + (TT - 1)) * 8 + lr] = v;
      else
        out[rowg * 8 + (lr - 8)] = v;
    }
  }
}

extern "C" void kernel_launch(void* const* d_in, const int* in_sizes, int n_in,
                              void* d_out, int out_size, void* d_ws, size_t ws_size,
                              hipStream_t stream) {
  const float* x    = (const float*)d_in[0];
  // d_in[1] = future (== 0), unused
  const float* Wih1 = (const float*)d_in[2];
  const float* Whh1 = (const float*)d_in[3];
  const float* bih1 = (const float*)d_in[4];
  const float* bhh1 = (const float*)d_in[5];
  const float* Wih2 = (const float*)d_in[6];
  const float* Whh2 = (const float*)d_in[7];
  const float* bih2 = (const float*)d_in[8];
  const float* bhh2 = (const float*)d_in[9];
  const float* W1   = (const float*)d_in[10];
  const float* b1   = (const float*)d_in[11];
  const float* W2   = (const float*)d_in[12];
  const float* b2   = (const float*)d_in[13];
  float* out = (float*)d_out;

  hipLaunchKernelGGL(lstm_fused, dim3(256), dim3(512), 0, stream,
                     x, Wih1, Whh1, bih1, bhh1, Wih2, Whh2, bih2, bhh2,
                     W1, b1, W2, b2, out);
}